// Round 5
// baseline (145.560 us; speedup 1.0000x reference)
//
#include <hip/hip_runtime.h>

typedef __attribute__((ext_vector_type(8))) short short8;
typedef __attribute__((ext_vector_type(4))) float floatx4;

// Problem constants
#define NEXP   36          // 12 tempers * 3 ops
#define NTOK   1024        // 128 batch * 8 patches
#define HOPS   4
#define NMEGA  160         // mega grid; all co-resident (<=256 CUs)

// Workspace layout (bytes)
#define OFF_STATE   0u          // 1024*256*4      = 1,048,576
#define OFF_W1B     1048576u    // 36*65536*2      = 4,718,592 (bf16, B-frag swizzled)
#define OFF_W2B     5767168u    // 36*65536*2      = 4,718,592
#define OFF_C1      10485760u   // 36*256*4        = 36,864
#define OFF_COUNTS  10522624u   // 4*36*4          = 576
#define OFF_LISTS   10523264u   // 4*36*1024*4     = 589,824
#define OFF_VER     11113088u   // 1024*4          = 4,096
#define OFF_DONE    11117184u   // 4               (end ~11.12 MB)

__device__ __forceinline__ unsigned short f2bf(float f) {
    unsigned u = __float_as_uint(f);
    u += 0x7FFFu + ((u >> 16) & 1u);   // round-to-nearest-even
    return (unsigned short)(u >> 16);
}

// ---------------------------------------------------------------------------
// PREP. r4 post-mortem fix: routing moved from bid 2916 (last — started in
// the SECOND scheduling wave, its ~4us serial walk extended the kernel tail)
// to bid 0 (first — fully overlapped with the 2880 convert blocks).
// Routing block also zeroes ver[] and done (replay-safe init: runs every
// graph iteration, no reliance on workspace poison values).
//  bid  0          : routing + ver/done zeroing.
//  bids [1,37)     : c1[e], e=bid-1.
//  bids [40,2920)  : weight convert; bb=bid-40, r=bb&7, q=bb>>3,
//                    e=r+8*(q>>6) (skip e>=36)  -> bid%8==e%8 XCD-affinity
//                    with the mega blocks that read expert e.
// ---------------------------------------------------------------------------
__global__ __launch_bounds__(256) void prep_kernel(
    const float* __restrict__ W1, const float* __restrict__ b1,
    const float* __restrict__ W2, const float* __restrict__ op_emb,
    const int* __restrict__ tempers, const int* __restrict__ ops,
    unsigned short* __restrict__ W1b, unsigned short* __restrict__ W2b,
    float* __restrict__ c1, int* __restrict__ counts, int* __restrict__ lists,
    int* __restrict__ ver, int* __restrict__ done)
{
    const int bid = blockIdx.x;
    const int t = threadIdx.x;

    if (bid == 0) {
        // ---- routing (single block; cumulative-halt semantics) ----
        __shared__ int lc[HOPS * NEXP];
        if (t < HOPS * NEXP) lc[t] = 0;
        for (int i = t; i < NTOK; i += 256) ver[i] = 0;   // token version ctrs
        if (t == 0) *done = 0;
        __syncthreads();
        for (int q = 0; q < 4; q++) {
            int n = q * 256 + t;
            bool act = true;
            for (int hop = 0; hop < HOPS; hop++) {
                int tt = tempers[hop * NTOK + n];
                int oo = ops[hop * NTOK + n];
                act = act && (tt != 12);       // 12 == halt; sticky
                if (act) {
                    int e = tt * 3 + oo;
                    int pos = atomicAdd(&lc[hop * NEXP + e], 1);
                    lists[(hop * NEXP + e) * NTOK + pos] = n;
                }
            }
        }
        __syncthreads();
        if (t < HOPS * NEXP) counts[t] = lc[t];
    } else if (bid < 37) {
        // ---- c1 precompute (fp32) ----
        const int e = bid - 1;
        __shared__ float eb[128];
        if (t < 128) eb[t] = op_emb[e * 128 + t];
        __syncthreads();
        float acc = b1[e * 256 + t];
        const float* wp = W1 + e * 98304 + 65536;  // emb rows of W1[e]
        #pragma unroll 4
        for (int k = 0; k < 128; k++)
            acc += eb[k] * wp[k * 256 + t];
        c1[e * 256 + t] = acc;
    } else if (bid >= 40) {
        // ---- weight convert + swizzle (XCD-affine) ----
        const int bb = bid - 40;
        const int r  = bb & 7;             // == bid%8 (40%8==0)
        const int q  = bb >> 3;
        const int e  = r + 8 * (q >> 6);
        if (e >= NEXP) return;
        const int sub = q & 63;
        const int mat = sub >> 5;          // 0: W1, 1: W2
        const int s2  = sub & 31;
        const int kb  = s2 >> 2;
        const int jt  = s2 & 3;
        const float* src = mat ? (W2 + e * 65536) : (W1 + e * 98304);
        unsigned short* dst = (mat ? W2b : W1b) + e * 65536;
        const int j  = jt * 64 + (t & 63);
        const int ks = (t >> 6) * 8;       // 8 consecutive k per thread
        short8 v;
        #pragma unroll
        for (int i = 0; i < 8; i++)
            v[i] = (short)f2bf(src[(kb * 32 + ks + i) * 256 + j]);  // coalesced across j
        *(short8*)(dst + (kb * 256 + j) * 32 + ks) = v;
    }
}

// ---------------------------------------------------------------------------
// MEGA: all four hops (per-token ver protocol, proven in r4) + FINAL folded
// in via a device-scope done-counter barrier.
//   - every block (working or not) increments done exactly once after its
//     hop work; blocks 0..127 then spin done==NMEGA and run the pool/LN/head
//     for batch b=bid. All NMEGA blocks co-resident -> deadlock-free.
//   - done zeroed by prep each iteration -> replay-safe (no poison reliance).
// Coherence protocol per tile publish (r4, verified): stores -> syncthreads
// (vmcnt drain into L2) -> t0 __threadfence (device writeback) -> barrier ->
// RELEASE fetch_add. Consumers: relaxed spin -> ACQUIRE reload -> barrier.
// B-frags preloaded ONCE into registers for all 4 hops; asm "+v" pin.
// bid -> e = bid%40 (bid%8==e%8 matches prep's writes), slot = bid/40.
// MFMA maps (m89): A[m=l&15][k=(l>>4)*8+i]; D col=l&15, row=(l>>4)*4+reg.
// ---------------------------------------------------------------------------
__global__ __launch_bounds__(1024, 4) void mega_kernel(
    const float* __restrict__ x, float* __restrict__ state,
    const unsigned short* __restrict__ W1b,
    const unsigned short* __restrict__ W2b,
    const float* __restrict__ c1, const float* __restrict__ b2,
    const int* __restrict__ counts, const int* __restrict__ lists,
    int* __restrict__ ver, int* __restrict__ done,
    const int* __restrict__ tempers,
    const float* __restrict__ ln_g, const float* __restrict__ ln_b,
    const float* __restrict__ Wt, const float* __restrict__ bt,
    float* __restrict__ out)
{
    const int bid  = blockIdx.x;
    const int e    = bid % 40;
    const int slot = bid / 40;
    const int t    = threadIdx.x;
    const int l = t & 63, w = t >> 6;      // wave 0..15
    const int col = l & 15, g = l >> 4;
    const int j = w * 16 + col;            // this wave's output column

    __shared__ int toks[16];
    __shared__ unsigned short Ab[4096];    // [kb][lane][8] bf16, 8 KB
    __shared__ unsigned short Hb[4096];    // 8 KB
    __shared__ float pool[4][256];         // final: partial pooled sums
    __shared__ float red[8];
    __shared__ float stats[2];
    __shared__ float pr[40];

    int ne[HOPS];
    bool work = false;
    if (e < NEXP) {
        #pragma unroll
        for (int h = 0; h < HOPS; h++) {
            ne[h] = counts[h * NEXP + e];
            work = work || (slot * 16 < ne[h]);
        }
    }

    if (work) {
        // ---- preload B-frags ONCE for all hops (register-resident) ----
        const unsigned short* Wp  = W1b + e * 65536;
        const unsigned short* Wp2 = W2b + e * 65536;
        short8 B1[8], B2[8];
        #pragma unroll
        for (int kb = 0; kb < 8; kb++) {
            B1[kb] = *(const short8*)(Wp  + (kb * 256 + j) * 32 + g * 8);
            B2[kb] = *(const short8*)(Wp2 + (kb * 256 + j) * 32 + g * 8);
        }
        #pragma unroll
        for (int kb = 0; kb < 8; kb++) {
            asm volatile("" : "+v"(B1[kb]));   // forbid remat-as-load
            asm volatile("" : "+v"(B2[kb]));
        }
        const float cv = c1[e * 256 + j];
        const float bv = b2[e * 256 + j];

        for (int hop = 0; hop < HOPS; hop++) {
            const float* src = hop ? state : x;
            for (int m0 = slot * 16; m0 < ne[hop]; m0 += 64) {
                const int mact = min(16, ne[hop] - m0);
                __syncthreads();               // toks/Ab reuse guard
                if (t < 16) {
                    int tok = (t < mact)
                            ? lists[(hop * NEXP + e) * NTOK + m0 + t] : -1;
                    toks[t] = tok;
                    if (hop > 0 && tok >= 0) {
                        // wait for this token's hop-(h-1) state write
                        while (__hip_atomic_load(&ver[tok], __ATOMIC_RELAXED,
                                                 __HIP_MEMORY_SCOPE_AGENT) < hop)
                            __builtin_amdgcn_s_sleep(1);
                        (void)__hip_atomic_load(&ver[tok], __ATOMIC_ACQUIRE,
                                                __HIP_MEMORY_SCOPE_AGENT);
                    }
                }
                __syncthreads();

                // ---- stage A tile: src rows (f32) -> bf16 A-frag layout ----
                {
                    int m = t >> 6;            // token row (one wave per row)
                    int k = (t & 63) * 4;      // float4 column
                    float4 v = make_float4(0.f, 0.f, 0.f, 0.f);
                    if (m < mact) v = *(const float4*)(src + toks[m] * 256 + k);
                    int kb = k >> 5, gg = (k >> 3) & 3, i = k & 7;
                    unsigned short* d = Ab + kb * 512 + (gg * 16 + m) * 8 + i;
                    d[0] = f2bf(v.x); d[1] = f2bf(v.y);
                    d[2] = f2bf(v.z); d[3] = f2bf(v.w);
                }
                __syncthreads();

                // ---- GEMM1 (weights in registers) ----
                floatx4 acc = (floatx4){cv, cv, cv, cv};
                #pragma unroll
                for (int kb = 0; kb < 8; kb++) {
                    short8 a = *(const short8*)(Ab + kb * 512 + l * 8);
                    acc = __builtin_amdgcn_mfma_f32_16x16x32_bf16(a, B1[kb], acc, 0, 0, 0);
                }
                // ---- epilogue 1: relu -> Hb in A-frag layout ----
                {
                    int kb2 = j >> 5, g2 = (j >> 3) & 3, i2 = j & 7;
                    #pragma unroll
                    for (int r = 0; r < 4; r++) {
                        int m = g * 4 + r;
                        float vv = acc[r];
                        vv = vv > 0.f ? vv : 0.f;
                        Hb[kb2 * 512 + (g2 * 16 + m) * 8 + i2] = f2bf(vv);
                    }
                }
                __syncthreads();

                // ---- GEMM2 ----
                floatx4 acc2 = (floatx4){bv, bv, bv, bv};
                #pragma unroll
                for (int kb = 0; kb < 8; kb++) {
                    short8 a = *(const short8*)(Hb + kb * 512 + l * 8);
                    acc2 = __builtin_amdgcn_mfma_f32_16x16x32_bf16(a, B2[kb], acc2, 0, 0, 0);
                }
                // ---- epilogue 2: relu -> state (f32), only real rows ----
                #pragma unroll
                for (int r = 0; r < 4; r++) {
                    int m = g * 4 + r;
                    if (m < mact) {
                        float vv = acc2[r];
                        state[toks[m] * 256 + j] = vv > 0.f ? vv : 0.f;
                    }
                }

                // ---- publish: make rows device-visible, bump version ----
                if (hop < HOPS - 1) {          // hop3 covered by done barrier
                    __syncthreads();           // drain stores into L2
                    if (t == 0) __threadfence();   // device-scope writeback
                    __syncthreads();
                    if (t < mact)
                        __hip_atomic_fetch_add(&ver[toks[t]], 1,
                                               __ATOMIC_RELEASE,
                                               __HIP_MEMORY_SCOPE_AGENT);
                }
            }
        }
    }

    // ---- done barrier: every block increments exactly once ----
    __syncthreads();                       // drain hop3 stores into L2
    if (t == 0) {
        __threadfence();                   // device-scope writeback
        __hip_atomic_fetch_add(done, 1, __ATOMIC_RELEASE,
                               __HIP_MEMORY_SCOPE_AGENT);
    }

    // ---- FINAL: blocks 0..127, one batch row each ----
    if (bid < 128) {
        if (t == 0) {
            while (__hip_atomic_load(done, __ATOMIC_RELAXED,
                                     __HIP_MEMORY_SCOPE_AGENT) < NMEGA)
                __builtin_amdgcn_s_sleep(2);
            (void)__hip_atomic_load(done, __ATOMIC_ACQUIRE,
                                    __HIP_MEMORY_SCOPE_AGENT);
        }
        __syncthreads();

        const int b = bid;
        {
            const int c = t & 255, grp = t >> 8;
            float s = 0.f;
            #pragma unroll
            for (int pp = 0; pp < 2; pp++) {
                int n = b * 8 + grp * 2 + pp;
                // tokens halted at hop 0 were never written -> read x
                const float* rowsrc = (tempers[n] != 12) ? state : x;
                s += rowsrc[n * 256 + c];
            }
            pool[grp][c] = s;
        }
        __syncthreads();
        float pooled = 0.f;
        if (t < 256) {
            pooled = (pool[0][t] + pool[1][t] + pool[2][t] + pool[3][t]) * 0.125f;
            float v1 = pooled, v2 = pooled * pooled;
            #pragma unroll
            for (int off = 32; off; off >>= 1) {
                v1 += __shfl_down(v1, off);
                v2 += __shfl_down(v2, off);
            }
            const int wq = t >> 6, lq = t & 63;
            if (lq == 0) { red[wq] = v1; red[4 + wq] = v2; }
        }
        __syncthreads();
        if (t == 0) {
            float su = red[0] + red[1] + red[2] + red[3];
            float sq = red[4] + red[5] + red[6] + red[7];
            float mu = su * (1.0f / 256.0f);
            float var = sq * (1.0f / 256.0f) - mu * mu;
            stats[0] = mu;
            stats[1] = rsqrtf(var + 1e-5f);
        }
        __syncthreads();
        if (t < 256) {
            float normed = (pooled - stats[0]) * stats[1] * ln_g[t] + ln_b[t];
            const int wq = t >> 6, lq = t & 63;
            #pragma unroll
            for (int c = 0; c < 10; c++) {
                float pv = normed * Wt[t * 10 + c];
                #pragma unroll
                for (int off = 32; off; off >>= 1) pv += __shfl_down(pv, off);
                if (lq == 0) pr[wq * 10 + c] = pv;
            }
        }
        __syncthreads();
        if (t < 10)
            out[b * 10 + t] = pr[t] + pr[10 + t] + pr[20 + t] + pr[30 + t] + bt[t];
    }
}

extern "C" void kernel_launch(void* const* d_in, const int* in_sizes, int n_in,
                              void* d_out, int out_size, void* d_ws, size_t ws_size,
                              hipStream_t stream)
{
    const float* x      = (const float*)d_in[0];
    const float* W1     = (const float*)d_in[1];
    const float* b1     = (const float*)d_in[2];
    const float* W2     = (const float*)d_in[3];
    const float* b2     = (const float*)d_in[4];
    const float* op_emb = (const float*)d_in[5];
    const float* ln_g   = (const float*)d_in[6];
    const float* ln_b   = (const float*)d_in[7];
    const float* Wt     = (const float*)d_in[8];
    const float* bt     = (const float*)d_in[9];
    const int* tempers  = (const int*)d_in[10];
    const int* ops      = (const int*)d_in[11];

    char* ws = (char*)d_ws;
    float* state          = (float*)(ws + OFF_STATE);
    unsigned short* W1b   = (unsigned short*)(ws + OFF_W1B);
    unsigned short* W2b   = (unsigned short*)(ws + OFF_W2B);
    float* c1             = (float*)(ws + OFF_C1);
    int* counts           = (int*)(ws + OFF_COUNTS);
    int* lists            = (int*)(ws + OFF_LISTS);
    int* ver              = (int*)(ws + OFF_VER);
    int* done             = (int*)(ws + OFF_DONE);
    float* out            = (float*)d_out;

    prep_kernel<<<2920, 256, 0, stream>>>(W1, b1, W2, op_emb, tempers, ops,
                                          W1b, W2b, c1, counts, lists,
                                          ver, done);
    mega_kernel<<<NMEGA, 1024, 0, stream>>>(x, state, W1b, W2b, c1, b2,
                                            counts, lists, ver, done,
                                            tempers, ln_g, ln_b, Wt, bt, out);
}

// Round 6
// 129.784 us; speedup vs baseline: 1.1216x; 1.1216x over previous
//
#include <hip/hip_runtime.h>

typedef __attribute__((ext_vector_type(8))) short short8;
typedef __attribute__((ext_vector_type(4))) float floatx4;

// Problem constants
#define NEXP   36          // 12 tempers * 3 ops
#define NTOK   1024        // 128 batch * 8 patches
#define HOPS   4

// Workspace layout (bytes)
#define OFF_STATE   0u          // 1024*256*4      = 1,048,576
#define OFF_W1B     1048576u    // 36*65536*2      = 4,718,592 (bf16, B-frag swizzled)
#define OFF_W2B     5767168u    // 36*65536*2      = 4,718,592
#define OFF_C1      10485760u   // 36*256*4        = 36,864
#define OFF_COUNTS  10522624u   // 4*36*4          = 576
#define OFF_LISTS   10523264u   // 4*36*1024*4     = 589,824
#define OFF_VER     11113088u   // 1024*4          = 4,096  (end ~11.12 MB)

__device__ __forceinline__ unsigned short f2bf(float f) {
    unsigned u = __float_as_uint(f);
    u += 0x7FFFu + ((u >> 16) & 1u);   // round-to-nearest-even
    return (unsigned short)(u >> 16);
}

// ---------------------------------------------------------------------------
// PREP (r5 layout, kept): routing at bid 0 so its ~4us serial walk overlaps
// the 2880 convert blocks (r4 had it LAST -> second scheduling wave -> pure
// kernel-tail extension). Routing block also zeroes ver[] (replay-safe).
//  bid  0          : routing + ver zeroing.
//  bids [1,37)     : c1[e], e=bid-1.
//  bids [40,2920)  : weight convert; bb=bid-40, r=bb&7, q=bb>>3,
//                    e=r+8*(q>>6) (skip e>=36) -> bid%8==e%8 XCD-affinity
//                    with the mega blocks that read expert e.
// ---------------------------------------------------------------------------
__global__ __launch_bounds__(256) void prep_kernel(
    const float* __restrict__ W1, const float* __restrict__ b1,
    const float* __restrict__ W2, const float* __restrict__ op_emb,
    const int* __restrict__ tempers, const int* __restrict__ ops,
    unsigned short* __restrict__ W1b, unsigned short* __restrict__ W2b,
    float* __restrict__ c1, int* __restrict__ counts, int* __restrict__ lists,
    int* __restrict__ ver)
{
    const int bid = blockIdx.x;
    const int t = threadIdx.x;

    if (bid == 0) {
        // ---- routing (single block; cumulative-halt semantics) ----
        __shared__ int lc[HOPS * NEXP];
        if (t < HOPS * NEXP) lc[t] = 0;
        for (int i = t; i < NTOK; i += 256) ver[i] = 0;   // token version ctrs
        __syncthreads();
        for (int q = 0; q < 4; q++) {
            int n = q * 256 + t;
            bool act = true;
            for (int hop = 0; hop < HOPS; hop++) {
                int tt = tempers[hop * NTOK + n];
                int oo = ops[hop * NTOK + n];
                act = act && (tt != 12);       // 12 == halt; sticky
                if (act) {
                    int e = tt * 3 + oo;
                    int pos = atomicAdd(&lc[hop * NEXP + e], 1);
                    lists[(hop * NEXP + e) * NTOK + pos] = n;
                }
            }
        }
        __syncthreads();
        if (t < HOPS * NEXP) counts[t] = lc[t];
    } else if (bid < 37) {
        // ---- c1 precompute (fp32) ----
        const int e = bid - 1;
        __shared__ float eb[128];
        if (t < 128) eb[t] = op_emb[e * 128 + t];
        __syncthreads();
        float acc = b1[e * 256 + t];
        const float* wp = W1 + e * 98304 + 65536;  // emb rows of W1[e]
        #pragma unroll 4
        for (int k = 0; k < 128; k++)
            acc += eb[k] * wp[k * 256 + t];
        c1[e * 256 + t] = acc;
    } else if (bid >= 40) {
        // ---- weight convert + swizzle (XCD-affine) ----
        const int bb = bid - 40;
        const int r  = bb & 7;             // == bid%8 (40%8==0)
        const int q  = bb >> 3;
        const int e  = r + 8 * (q >> 6);
        if (e >= NEXP) return;
        const int sub = q & 63;
        const int mat = sub >> 5;          // 0: W1, 1: W2
        const int s2  = sub & 31;
        const int kb  = s2 >> 2;
        const int jt  = s2 & 3;
        const float* src = mat ? (W2 + e * 65536) : (W1 + e * 98304);
        unsigned short* dst = (mat ? W2b : W1b) + e * 65536;
        const int j  = jt * 64 + (t & 63);
        const int ks = (t >> 6) * 8;       // 8 consecutive k per thread
        short8 v;
        #pragma unroll
        for (int i = 0; i < 8; i++)
            v[i] = (short)f2bf(src[(kb * 32 + ks + i) * 256 + j]);  // coalesced across j
        *(short8*)(dst + (kb * 256 + j) * 32 + ks) = v;
    }
}

// ---------------------------------------------------------------------------
// MEGA-HOP (r4 structure, reverted from r5's done-barrier folding — r5
// post-mortem: folding final in cost ~10us; separate 2us final is cheaper).
// All four hops in one launch, per-token ver protocol:
//   producer: stores -> __syncthreads (vmcnt drain: stores at L2)
//             -> t0 __threadfence (wbl2, device writeback) -> barrier
//             -> RELAXED fetch_add ver[tok]   (r6: was RELEASE; the explicit
//                fence already ordered the data, RELEASE re-emitted a second
//                wbl2 per tile on the critical chain)
//   consumer: relaxed spin -> ACQUIRE reload (L1/L2 inv) -> barrier -> read
// Deadlock-free: all 160 blocks co-resident; hop-h spins depend only on
// hop-(h-1) work which precedes any spin in program order.
// B-frags preloaded ONCE into registers for all 4 hops; asm "+v" pin.
// bid -> e = bid%40 (bid%8==e%8 matches prep's writes), slot = bid/40.
// MFMA maps (m89): A[m=l&15][k=(l>>4)*8+i]; D col=l&15, row=(l>>4)*4+reg.
// ---------------------------------------------------------------------------
__global__ __launch_bounds__(1024, 4) void mega_hop_kernel(
    const float* __restrict__ x, float* __restrict__ state,
    const unsigned short* __restrict__ W1b,
    const unsigned short* __restrict__ W2b,
    const float* __restrict__ c1, const float* __restrict__ b2,
    const int* __restrict__ counts, const int* __restrict__ lists,
    int* __restrict__ ver)
{
    const int e    = blockIdx.x % 40;
    const int slot = blockIdx.x / 40;
    if (e >= NEXP) return;

    int ne[HOPS];
    bool any = false;
    #pragma unroll
    for (int h = 0; h < HOPS; h++) {
        ne[h] = counts[h * NEXP + e];
        any = any || (slot * 16 < ne[h]);
    }
    if (!any) return;                      // no tile in any hop for this slot

    const int t = threadIdx.x;
    const int l = t & 63, w = t >> 6;      // wave 0..15
    const int col = l & 15, g = l >> 4;
    const int j = w * 16 + col;            // this wave's output column

    // ---- preload B-frags ONCE for all hops (register-resident) ----
    const unsigned short* Wp  = W1b + e * 65536;
    const unsigned short* Wp2 = W2b + e * 65536;
    short8 B1[8], B2[8];
    #pragma unroll
    for (int kb = 0; kb < 8; kb++) {
        B1[kb] = *(const short8*)(Wp  + (kb * 256 + j) * 32 + g * 8);
        B2[kb] = *(const short8*)(Wp2 + (kb * 256 + j) * 32 + g * 8);
    }
    #pragma unroll
    for (int kb = 0; kb < 8; kb++) {
        asm volatile("" : "+v"(B1[kb]));   // forbid remat-as-load
        asm volatile("" : "+v"(B2[kb]));
    }
    const float cv = c1[e * 256 + j];
    const float bv = b2[e * 256 + j];

    __shared__ int toks[16];
    __shared__ unsigned short Ab[4096];    // [kb][lane][8] bf16, 8 KB
    __shared__ unsigned short Hb[4096];    // 8 KB

    for (int hop = 0; hop < HOPS; hop++) {
        const float* src = hop ? state : x;
        for (int m0 = slot * 16; m0 < ne[hop]; m0 += 64) {
            const int mact = min(16, ne[hop] - m0);
            __syncthreads();               // toks/Ab reuse guard
            if (t < 16) {
                int tok = (t < mact)
                        ? lists[(hop * NEXP + e) * NTOK + m0 + t] : -1;
                toks[t] = tok;
                if (hop > 0 && tok >= 0) {
                    // wait for this token's hop-(h-1) state write
                    while (__hip_atomic_load(&ver[tok], __ATOMIC_RELAXED,
                                             __HIP_MEMORY_SCOPE_AGENT) < hop)
                        __builtin_amdgcn_s_sleep(1);
                    (void)__hip_atomic_load(&ver[tok], __ATOMIC_ACQUIRE,
                                            __HIP_MEMORY_SCOPE_AGENT);
                }
            }
            __syncthreads();

            // ---- stage A tile: src rows (f32) -> bf16 in A-frag layout ----
            {
                int m = t >> 6;            // token row 0..15 (one wave per row)
                int k = (t & 63) * 4;      // float4 column
                float4 v = make_float4(0.f, 0.f, 0.f, 0.f);
                if (m < mact) v = *(const float4*)(src + toks[m] * 256 + k);
                int kb = k >> 5, gg = (k >> 3) & 3, i = k & 7;
                unsigned short* d = Ab + kb * 512 + (gg * 16 + m) * 8 + i;
                d[0] = f2bf(v.x); d[1] = f2bf(v.y);
                d[2] = f2bf(v.z); d[3] = f2bf(v.w);
            }
            __syncthreads();

            // ---- GEMM1 (weights in registers) ----
            floatx4 acc = (floatx4){cv, cv, cv, cv};
            #pragma unroll
            for (int kb = 0; kb < 8; kb++) {
                short8 a = *(const short8*)(Ab + kb * 512 + l * 8);
                acc = __builtin_amdgcn_mfma_f32_16x16x32_bf16(a, B1[kb], acc, 0, 0, 0);
            }
            // ---- epilogue 1: relu -> Hb in A-frag layout ----
            {
                int kb2 = j >> 5, g2 = (j >> 3) & 3, i2 = j & 7;
                #pragma unroll
                for (int r = 0; r < 4; r++) {
                    int m = g * 4 + r;
                    float vv = acc[r];
                    vv = vv > 0.f ? vv : 0.f;
                    Hb[kb2 * 512 + (g2 * 16 + m) * 8 + i2] = f2bf(vv);
                }
            }
            __syncthreads();

            // ---- GEMM2 ----
            floatx4 acc2 = (floatx4){bv, bv, bv, bv};
            #pragma unroll
            for (int kb = 0; kb < 8; kb++) {
                short8 a = *(const short8*)(Hb + kb * 512 + l * 8);
                acc2 = __builtin_amdgcn_mfma_f32_16x16x32_bf16(a, B2[kb], acc2, 0, 0, 0);
            }
            // ---- epilogue 2: relu -> state (f32), only real rows ----
            #pragma unroll
            for (int r = 0; r < 4; r++) {
                int m = g * 4 + r;
                if (m < mact) {
                    float vv = acc2[r];
                    state[toks[m] * 256 + j] = vv > 0.f ? vv : 0.f;
                }
            }

            // ---- publish: make rows device-visible, bump version ----
            if (hop < HOPS - 1) {          // hop3 consumed after kernel end
                __syncthreads();           // drain all waves' stores into L2
                if (t == 0) __threadfence();   // device-scope L2 writeback
                __syncthreads();
                if (t < mact)
                    __hip_atomic_fetch_add(&ver[toks[t]], 1, __ATOMIC_RELAXED,
                                           __HIP_MEMORY_SCOPE_AGENT);
            }
        }
    }
}

// ---------------------------------------------------------------------------
// FINAL: mean-pool 8 patches -> LayerNorm -> 10-class head. One block/batch.
// Tokens halted at hop 0 were never written to state -> read x instead.
// ---------------------------------------------------------------------------
__global__ __launch_bounds__(256) void final_kernel(
    const float* __restrict__ x, const float* __restrict__ state,
    const int* __restrict__ tempers,
    const float* __restrict__ ln_g, const float* __restrict__ ln_b,
    const float* __restrict__ Wt, const float* __restrict__ bt,
    float* __restrict__ out)
{
    const int b = blockIdx.x, t = threadIdx.x;
    float s = 0.f;
    #pragma unroll
    for (int p = 0; p < 8; p++) {
        int n = b * 8 + p;
        const float* rowsrc = (tempers[n] != 12) ? state : x;
        s += rowsrc[n * 256 + t];
    }
    s *= 0.125f;

    float v1 = s, v2 = s * s;
    #pragma unroll
    for (int off = 32; off; off >>= 1) {
        v1 += __shfl_down(v1, off);
        v2 += __shfl_down(v2, off);
    }
    __shared__ float red[8];
    __shared__ float stats[2];
    const int w = t >> 6, l = t & 63;
    if (l == 0) { red[w] = v1; red[4 + w] = v2; }
    __syncthreads();
    if (t == 0) {
        float su = red[0] + red[1] + red[2] + red[3];
        float sq = red[4] + red[5] + red[6] + red[7];
        float mu = su * (1.0f / 256.0f);
        float var = sq * (1.0f / 256.0f) - mu * mu;
        stats[0] = mu;
        stats[1] = rsqrtf(var + 1e-5f);
    }
    __syncthreads();
    float normed = (s - stats[0]) * stats[1] * ln_g[t] + ln_b[t];

    __shared__ float pr[40];
    #pragma unroll
    for (int c = 0; c < 10; c++) {
        float pv = normed * Wt[t * 10 + c];
        #pragma unroll
        for (int off = 32; off; off >>= 1) pv += __shfl_down(pv, off);
        if (l == 0) pr[w * 10 + c] = pv;
    }
    __syncthreads();
    if (t < 10)
        out[b * 10 + t] = pr[t] + pr[10 + t] + pr[20 + t] + pr[30 + t] + bt[t];
}

extern "C" void kernel_launch(void* const* d_in, const int* in_sizes, int n_in,
                              void* d_out, int out_size, void* d_ws, size_t ws_size,
                              hipStream_t stream)
{
    const float* x      = (const float*)d_in[0];
    const float* W1     = (const float*)d_in[1];
    const float* b1     = (const float*)d_in[2];
    const float* W2     = (const float*)d_in[3];
    const float* b2     = (const float*)d_in[4];
    const float* op_emb = (const float*)d_in[5];
    const float* ln_g   = (const float*)d_in[6];
    const float* ln_b   = (const float*)d_in[7];
    const float* Wt     = (const float*)d_in[8];
    const float* bt     = (const float*)d_in[9];
    const int* tempers  = (const int*)d_in[10];
    const int* ops      = (const int*)d_in[11];

    char* ws = (char*)d_ws;
    float* state          = (float*)(ws + OFF_STATE);
    unsigned short* W1b   = (unsigned short*)(ws + OFF_W1B);
    unsigned short* W2b   = (unsigned short*)(ws + OFF_W2B);
    float* c1             = (float*)(ws + OFF_C1);
    int* counts           = (int*)(ws + OFF_COUNTS);
    int* lists            = (int*)(ws + OFF_LISTS);
    int* ver              = (int*)(ws + OFF_VER);
    float* out            = (float*)d_out;

    prep_kernel<<<2920, 256, 0, stream>>>(W1, b1, W2, op_emb, tempers, ops,
                                          W1b, W2b, c1, counts, lists, ver);
    mega_hop_kernel<<<160, 1024, 0, stream>>>(x, state, W1b, W2b, c1, b2,
                                              counts, lists, ver);
    final_kernel<<<128, 256, 0, stream>>>(x, state, tempers,
                                          ln_g, ln_b, Wt, bt, out);
}